// Round 4
// baseline (416.615 us; speedup 1.0000x reference)
//
#include <hip/hip_runtime.h>

// ---------------------------------------------------------------------------
// RefinedQuantumEntanglementLayer on MI355X (gfx950)
//
// out = (l2norm(x) @ expm(Mr-Mr^T) @ expm(Mi-Mi^T) + bias)^2 * softmax(qg)
//
// expm via scaling-and-squaring: X = A/8, degree-12 Taylor (Paterson-
// Stockmeyer), 3 squarings, plain bf16 with f32 accum (41x margin, r2/r3).
//
// All GEMMs are f(A,B) = A*B^T (both operands row-major K-contiguous).
// Transposed partners produced by DUAL-WRITE epilogue (tile (bi,bj) of D
// also written as tile (bj,bi) of D^T).
//   X2 = -f(X,X); X3 = -f(X2,X); X4 = f(X2,X2)
//   P2 = f(P1,X4)+q1;  E = f(P2,X4)+q0 [dual -> Et]
//   squarings: E' = f(E,Et) [dual -> E't]
//   W = U^T = f(E3t_B, E3_A); main: out = f(Xn,W) epi (.+bias)^2*gate
//
// r4: chain GEMM is LDS-free and barrier-free. The 2MB operands are
// L2-resident; staging them cost a vmcnt(0)+barrier drain per k-step at
// 2 blocks/CU (r3: ~15us/round vs ~6us floor). Now each wave owns an
// independent 32x32 tile, streams fragments straight from L2, and the
// compiler software-pipelines the k-loop with counted vmcnt -- no sync
// points anywhere in the kernel.
// ---------------------------------------------------------------------------

typedef unsigned int u32;
typedef unsigned short u16;
typedef __attribute__((ext_vector_type(8))) short short8;   // 8 x bf16 raw
typedef __attribute__((ext_vector_type(4))) float f32x4;

#define GLOBAL_AS __attribute__((address_space(1)))
#define LDS_AS    __attribute__((address_space(3)))

constexpr int D = 1024;
constexpr float EXPM_SCALE = 1.0f / 8.0f;   // s = 3 squarings

__device__ __forceinline__ u16 f2bf(float f) {
  union { float f; u32 u; } v; v.f = f;
  u32 r = (v.u + 0x7FFFu + ((v.u >> 16) & 1u)) >> 16;
  return (u16)r;
}
__device__ __forceinline__ float bf2f(u16 u) {
  union { u32 u; float f; } v; v.u = ((u32)u) << 16;
  return v.f;
}

// async global->LDS, 16B per lane; lds base must be wave-uniform.
__device__ __forceinline__ void g2l16(const void* g, void* l) {
  __builtin_amdgcn_global_load_lds((const GLOBAL_AS u32*)g, (LDS_AS u32*)l,
                                   16, 0, 0);
}

// ---------------------------------------------------------------------------
// normalize rows of x -> bf16
__global__ __launch_bounds__(256) void normalize_kernel(
    const float* __restrict__ x, u16* __restrict__ Xn) {
  const int r = blockIdx.x;
  const int t = threadIdx.x;
  const float4 v = ((const float4*)(x + (size_t)r * D))[t];
  float ss = v.x * v.x + v.y * v.y + v.z * v.z + v.w * v.w;
  for (int o = 32; o; o >>= 1) ss += __shfl_down(ss, o);
  __shared__ float s4[4];
  if ((t & 63) == 0) s4[t >> 6] = ss;
  __syncthreads();
  const float tot = s4[0] + s4[1] + s4[2] + s4[3];
  const float inv = rsqrtf(fmaxf(tot, 1e-12f));
  ushort4 o4;
  o4.x = f2bf(v.x * inv); o4.y = f2bf(v.y * inv);
  o4.z = f2bf(v.z * inv); o4.w = f2bf(v.w * inv);
  ((ushort4*)(Xn + (size_t)r * D))[t] = o4;
}

// ---------------------------------------------------------------------------
// softmax over D=1024 values, one block of 1024 threads
__global__ __launch_bounds__(1024) void gate_kernel(
    const float* __restrict__ g, float* __restrict__ pout) {
  __shared__ float red[16];
  const int t = threadIdx.x;
  const float v = g[t];
  float m = v;
  for (int o = 32; o; o >>= 1) m = fmaxf(m, __shfl_xor(m, o));
  if ((t & 63) == 0) red[t >> 6] = m;
  __syncthreads();
  float M = red[0];
  for (int i = 1; i < 16; ++i) M = fmaxf(M, red[i]);
  const float e = __expf(v - M);
  float s = e;
  for (int o = 32; o; o >>= 1) s += __shfl_xor(s, o);
  __syncthreads();
  if ((t & 63) == 0) red[t >> 6] = s;
  __syncthreads();
  float S = 0.f;
  for (int i = 0; i < 16; ++i) S += red[i];
  pout[t] = e / S;
}

// ---------------------------------------------------------------------------
// X = (M - M^T) * EXPM_SCALE -> bf16.  z: 0 -> Mr, 1 -> Mi
__global__ __launch_bounds__(256) void skew_kernel(
    const float* __restrict__ Mr, const float* __restrict__ Mi,
    u16* X0, u16* X1) {
  const float* M = (blockIdx.z == 0) ? Mr : Mi;
  u16* X = (blockIdx.z == 0) ? X0 : X1;
  __shared__ float t2[64][67];
  const int t = threadIdx.x, bi = blockIdx.x, bj = blockIdx.y;
  const int r0 = t >> 4, c0 = (t & 15) * 4;
  float4 own[4];
#pragma unroll
  for (int i = 0; i < 4; ++i) {
    const int r = i * 16 + r0;
    own[i] = *(const float4*)(M + (size_t)(bi * 64 + r) * D + bj * 64 + c0);
    const float4 tr =
        *(const float4*)(M + (size_t)(bj * 64 + r) * D + bi * 64 + c0);
    t2[r][c0 + 0] = tr.x; t2[r][c0 + 1] = tr.y;
    t2[r][c0 + 2] = tr.z; t2[r][c0 + 3] = tr.w;
  }
  __syncthreads();
#pragma unroll
  for (int i = 0; i < 4; ++i) {
    const int r = i * 16 + r0;
    const float o[4] = {own[i].x, own[i].y, own[i].z, own[i].w};
    ushort4 hv;
    u16* hp = (u16*)&hv;
#pragma unroll
    for (int j = 0; j < 4; ++j)
      hp[j] = f2bf((o[j] - t2[c0 + j][r]) * EXPM_SCALE);
    *(ushort4*)(X + (size_t)(bi * 64 + r) * D + bj * 64 + c0) = hv;
  }
}

// ---------------------------------------------------------------------------
// build q0, q1 (f32) and P1 (bf16) from X..X4 elementwise.
struct QJob {
  const u16 *X, *X2, *X3, *X4;
  float *q0, *q1;
  u16 *P1;
};
struct QJobs { QJob j[2]; };
__global__ __launch_bounds__(256) void build_q_kernel(QJobs jobs) {
  const QJob jb = jobs.j[blockIdx.y];
  const size_t idx0 = ((size_t)blockIdx.x * 256 + threadIdx.x) * 4;
  const int i = (int)(idx0 >> 10);
  const int j0 = (int)(idx0 & 1023);
  const ushort4 xv = *(const ushort4*)(jb.X + idx0);
  const ushort4 x2v = *(const ushort4*)(jb.X2 + idx0);
  const ushort4 x3v = *(const ushort4*)(jb.X3 + idx0);
  const ushort4 x4v = *(const ushort4*)(jb.X4 + idx0);
  float4 q0v, q1v;
  ushort4 p1v;
  u16* p1p = (u16*)&p1v;
  constexpr float c8 = 1.f / 40320.f, c9 = 1.f / 362880.f,
                  c10 = 1.f / 3628800.f, c11 = 1.f / 39916800.f,
                  c12 = 1.f / 479001600.f;
#pragma unroll
  for (int k = 0; k < 4; ++k) {
    const float d = (i == (j0 + k)) ? 1.f : 0.f;
    const float x = bf2f(((const u16*)&xv)[k]);
    const float x2 = bf2f(((const u16*)&x2v)[k]);
    const float x3 = bf2f(((const u16*)&x3v)[k]);
    const float x4 = bf2f(((const u16*)&x4v)[k]);
    ((float*)&q0v)[k] = d + x + x2 * 0.5f + x3 * (1.f / 6.f);
    ((float*)&q1v)[k] = d * (1.f / 24.f) + x * (1.f / 120.f) +
                        x2 * (1.f / 720.f) + x3 * (1.f / 5040.f);
    p1p[k] = f2bf(d * c8 + x * c9 + x2 * c10 + x3 * c11 + x4 * c12);
  }
  *(float4*)(jb.q0 + idx0) = q0v;
  *(float4*)(jb.q1 + idx0) = q1v;
  *(ushort4*)(jb.P1 + idx0) = p1v;
}

// ---------------------------------------------------------------------------
// chain GEMM: Dst = alpha*(A*B^T) [+ C], optional dual transposed write DT.
// LDS-free / barrier-free: 4 independent waves per block, each wave owns a
// 32x32 output tile (2x2 of 16x16x32 MFMA), fragments streamed straight
// from L2-resident global memory. Grid: (256 tiles/4, z).
struct CJob {
  const u16 *A, *B;
  const float* C;
  u16 *Dst, *DT;
  float alpha;
};
struct CJobs { CJob j[4]; };
__global__ __launch_bounds__(256) void gemm_chain_kernel(CJobs jobs) {
  const CJob jb = jobs.j[blockIdx.y];
  const int w = threadIdx.x >> 6, lane = threadIdx.x & 63;
  const int tile = blockIdx.x * 4 + w;      // 1024 tiles = 32 x 32
  const int ti = tile >> 5, tj = tile & 31;

  f32x4 acc[2][2];
#pragma unroll
  for (int m = 0; m < 2; ++m)
#pragma unroll
    for (int n = 0; n < 2; ++n) acc[m][n] = f32x4{0.f, 0.f, 0.f, 0.f};

  // lane holds A[row = base + (lane&15)][k = kbase + (lane>>4)*8 .. +7]
  const u16* Ab = jb.A + (size_t)(ti * 32 + (lane & 15)) * D + (lane >> 4) * 8;
  const u16* Bb = jb.B + (size_t)(tj * 32 + (lane & 15)) * D + (lane >> 4) * 8;

#pragma unroll 2
  for (int kt = 0; kt < 16; ++kt) {
    const int k0 = kt * 64;
    short8 a[2][2], b[2][2];  // [h][m]
#pragma unroll
    for (int h = 0; h < 2; ++h)
#pragma unroll
      for (int m = 0; m < 2; ++m) {
        a[h][m] = *(const short8*)(Ab + (size_t)(m * 16) * D + k0 + h * 32);
        b[h][m] = *(const short8*)(Bb + (size_t)(m * 16) * D + k0 + h * 32);
      }
#pragma unroll
    for (int h = 0; h < 2; ++h)
#pragma unroll
      for (int m = 0; m < 2; ++m)
#pragma unroll
        for (int n = 0; n < 2; ++n)
          acc[m][n] = __builtin_amdgcn_mfma_f32_16x16x32_bf16(
              a[h][m], b[h][n], acc[m][n], 0, 0, 0);
  }

  const int or0 = ti * 32, oc0 = tj * 32;
#pragma unroll
  for (int m = 0; m < 2; ++m)
#pragma unroll
    for (int n = 0; n < 2; ++n) {
      const int row0 = or0 + m * 16 + (lane >> 4) * 4;
      const int col = oc0 + n * 16 + (lane & 15);
      ushort4 dv;
      u16* dp = (u16*)&dv;
#pragma unroll
      for (int r = 0; r < 4; ++r) {
        float v = acc[m][n][r] * jb.alpha;
        if (jb.C) v += jb.C[(size_t)(row0 + r) * D + col];
        dp[r] = f2bf(v);
        jb.Dst[(size_t)(row0 + r) * D + col] = dp[r];
      }
      if (jb.DT)  // transposed tile: DT[col][row0..row0+3], one 8B store
        *(ushort4*)(jb.DT + (size_t)col * D + row0) = dv;
    }
}

// ---------------------------------------------------------------------------
// main GEMM: out[r][c] = (sum_k Xn[r][k]*W[c][k] + bias[c])^2 * gate[c]
// 128x128 tile, BK=64, 4 waves (2x2, 64x64 each). Natural (bi fastest)
// block order -- XCD swizzle measured SLOWER here (r2: +22us).
__global__ __launch_bounds__(256) void main_gemm_kernel(
    const u16* __restrict__ Xn, const u16* __restrict__ Wm,
    const float* __restrict__ bias, const float* __restrict__ gate,
    float* __restrict__ out) {
  const int tid = threadIdx.x;
  const int w = tid >> 6, lane = tid & 63;
  const int wr = w >> 1, wc = w & 1;
  __shared__ u16 ldsA[128 * 64], ldsB[128 * 64];
  f32x4 acc[4][4];
#pragma unroll
  for (int m = 0; m < 4; ++m)
#pragma unroll
    for (int n = 0; n < 4; ++n) acc[m][n] = f32x4{0.f, 0.f, 0.f, 0.f};

  const int bi = blockIdx.x, bj = blockIdx.y;
  const int r_l = lane >> 3, c_l = lane & 7;

  for (int kt = 0; kt < 16; ++kt) {
    const int k0 = kt * 64;
#pragma unroll
    for (int p = 0; p < 4; ++p) {
      const int row = p * 32 + w * 8 + r_l;
      const int chunk = c_l ^ (row & 7);
      g2l16(Xn + (size_t)(bi * 128 + row) * D + k0 + chunk * 8,
            (u16*)((char*)ldsA + p * 4096 + w * 1024));
      g2l16(Wm + (size_t)(bj * 128 + row) * D + k0 + chunk * 8,
            (u16*)((char*)ldsB + p * 4096 + w * 1024));
    }
    __syncthreads();
#pragma unroll
    for (int h = 0; h < 2; ++h) {
      short8 a[4], b[4];
      const int kk = h * 32 + (lane >> 4) * 8;
#pragma unroll
      for (int m = 0; m < 4; ++m) {
        const int row = wr * 64 + m * 16 + (lane & 15);
        const int off = row * 128 + ((kk * 2) ^ ((row & 7) << 4));
        a[m] = *(const short8*)((const char*)ldsA + off);
      }
#pragma unroll
      for (int n = 0; n < 4; ++n) {
        const int row = wc * 64 + n * 16 + (lane & 15);
        const int off = row * 128 + ((kk * 2) ^ ((row & 7) << 4));
        b[n] = *(const short8*)((const char*)ldsB + off);
      }
#pragma unroll
      for (int m = 0; m < 4; ++m)
#pragma unroll
        for (int n = 0; n < 4; ++n)
          acc[m][n] = __builtin_amdgcn_mfma_f32_16x16x32_bf16(
              a[m], b[n], acc[m][n], 0, 0, 0);
    }
    __syncthreads();
  }
  const int or0 = bi * 128 + wr * 64, oc0 = bj * 128 + wc * 64;
#pragma unroll
  for (int m = 0; m < 4; ++m)
#pragma unroll
    for (int n = 0; n < 4; ++n)
#pragma unroll
      for (int r = 0; r < 4; ++r) {
        const int row = or0 + m * 16 + (lane >> 4) * 4 + r;
        const int col = oc0 + n * 16 + (lane & 15);
        const float t = acc[m][n][r] + bias[col];
        out[(size_t)row * D + col] = t * t * gate[col];
      }
}

// ---------------------------------------------------------------------------
extern "C" void kernel_launch(void* const* d_in, const int* in_sizes, int n_in,
                              void* d_out, int out_size, void* d_ws,
                              size_t ws_size, hipStream_t stream) {
  (void)in_sizes; (void)n_in; (void)out_size; (void)ws_size;
  const float* inp = (const float*)d_in[0];
  const float* Mr = (const float*)d_in[1];
  const float* Mi = (const float*)d_in[2];
  const float* bias = (const float*)d_in[3];
  const float* qg = (const float*)d_in[4];
  float* out = (float*)d_out;
  float* gate_out = out + (size_t)32768 * 1024;

  char* ws = (char*)d_ws;
  u16* Xn = (u16*)ws;  // 64 MB
  // per-matrix region (20 MB): 6 bf16 slots (2 MB) + q0,q1 (4 MB f32).
  // slot lifetimes: s0 X->E3, s1 X2->E3t, s2 X3->E1, s3 X4->E2,
  //                 s4 P1->E1t, s5 P2->E2t
  auto slot = [&](int m, int s) -> u16* {
    return (u16*)(ws + 67108864 + (size_t)m * 20971520 + (size_t)s * 2097152);
  };
  auto q0p = [&](int m) -> float* {
    return (float*)(ws + 67108864 + (size_t)m * 20971520 + 12582912);
  };
  auto q1p = [&](int m) -> float* {
    return (float*)(ws + 67108864 + (size_t)m * 20971520 + 16777216);
  };
  u16* W = (u16*)(ws + 67108864 + 2 * 20971520);  // 2 MB; total ~108 MB

  normalize_kernel<<<32768, 256, 0, stream>>>(inp, Xn);
  gate_kernel<<<1, 1024, 0, stream>>>(qg, gate_out);
  skew_kernel<<<dim3(16, 16, 2), 256, 0, stream>>>(Mr, Mi, slot(0, 0),
                                                   slot(1, 0));

  CJobs cj{};
  // C1: X2 = -f(X,X) -> s1
  for (int m = 0; m < 2; ++m)
    cj.j[m] = CJob{slot(m, 0), slot(m, 0), nullptr, slot(m, 1), nullptr, -1.f};
  gemm_chain_kernel<<<dim3(256, 2), 256, 0, stream>>>(cj);
  // C2: X3 = -f(X2,X) -> s2 ; X4 = f(X2,X2) -> s3
  for (int m = 0; m < 2; ++m) {
    cj.j[m * 2 + 0] =
        CJob{slot(m, 1), slot(m, 0), nullptr, slot(m, 2), nullptr, -1.f};
    cj.j[m * 2 + 1] =
        CJob{slot(m, 1), slot(m, 1), nullptr, slot(m, 3), nullptr, 1.f};
  }
  gemm_chain_kernel<<<dim3(256, 4), 256, 0, stream>>>(cj);
  // buildq: q0, q1, P1 -> s4
  QJobs qj{};
  for (int m = 0; m < 2; ++m)
    qj.j[m] = QJob{slot(m, 0), slot(m, 1), slot(m, 2), slot(m, 3),
                   q0p(m),     q1p(m),     slot(m, 4)};
  build_q_kernel<<<dim3(1024, 2), 256, 0, stream>>>(qj);
  // C3: P2 = f(P1,X4)+q1 -> s5
  for (int m = 0; m < 2; ++m)
    cj.j[m] = CJob{slot(m, 4), slot(m, 3), q1p(m), slot(m, 5), nullptr, 1.f};
  gemm_chain_kernel<<<dim3(256, 2), 256, 0, stream>>>(cj);
  // C4: E = f(P2,X4)+q0 -> s0, dual Et -> s1   (X, X2 dead)
  for (int m = 0; m < 2; ++m)
    cj.j[m] = CJob{slot(m, 5), slot(m, 3), q0p(m), slot(m, 0), slot(m, 1), 1.f};
  gemm_chain_kernel<<<dim3(256, 2), 256, 0, stream>>>(cj);
  // sq1: E1 = f(E,Et) -> s2, dual E1t -> s4   (X3, P1 dead)
  for (int m = 0; m < 2; ++m)
    cj.j[m] = CJob{slot(m, 0), slot(m, 1), nullptr, slot(m, 2), slot(m, 4), 1.f};
  gemm_chain_kernel<<<dim3(256, 2), 256, 0, stream>>>(cj);
  // sq2: E2 = f(E1,E1t) -> s3, dual E2t -> s5   (X4, P2 dead)
  for (int m = 0; m < 2; ++m)
    cj.j[m] = CJob{slot(m, 2), slot(m, 4), nullptr, slot(m, 3), slot(m, 5), 1.f};
  gemm_chain_kernel<<<dim3(256, 2), 256, 0, stream>>>(cj);
  // sq3: E3 = f(E2,E2t) -> s0, dual E3t -> s1   (E, Et dead)
  for (int m = 0; m < 2; ++m)
    cj.j[m] = CJob{slot(m, 3), slot(m, 5), nullptr, slot(m, 0), slot(m, 1), 1.f};
  gemm_chain_kernel<<<dim3(256, 2), 256, 0, stream>>>(cj);
  // W = U^T = f(E3t_B, E3_A)
  cj.j[0] = CJob{slot(1, 1), slot(0, 0), nullptr, W, nullptr, 1.f};
  gemm_chain_kernel<<<dim3(256, 1), 256, 0, stream>>>(cj);

  main_gemm_kernel<<<dim3(256, 8), 256, 0, stream>>>(Xn, W, bias, gate_out,
                                                     out);
}

// Round 5
// 272.648 us; speedup vs baseline: 1.5280x; 1.5280x over previous
//
#include <hip/hip_runtime.h>

// ---------------------------------------------------------------------------
// RefinedQuantumEntanglementLayer on MI355X (gfx950)
//
// out = (l2norm(x) @ expm(Mr-Mr^T) @ expm(Mi-Mi^T) + bias)^2 * softmax(qg)
//
// expm via scaling-and-squaring: X = A/8, degree-12 Taylor (Paterson-
// Stockmeyer), 3 squarings, plain bf16 with f32 accum (41x margin, r2/r3).
//
// All GEMMs are f(A,B) = A*B^T (both operands row-major K-contiguous).
// Transposed partners produced by DUAL-WRITE epilogue (tile (bi,bj) of D
// also written as tile (bj,bi) of D^T).
//   X2 = -f(X,X); X3 = -f(X2,X); X4 = f(X2,X2)
//   P2 = f(P1,X4)+q1;  E = f(P2,X4)+q0 [dual -> Et]
//   squarings: E' = f(E,Et) [dual -> E't]
//   W = U^T = f(E3t_B, E3_A); main: out = f(Xn,W) epi (.+bias)^2*gate
//
// r5: chain reverted to r3's LDS dbuf kernel (r4's LDS-free chain regressed
// 2x: private per-wave loads at 2 waves/SIMD cannot hide L2 latency).
// Main GEMM upgraded: 256x256 tile, 8 waves (2x4, 128x64 each), 128 KiB
// double-buffered LDS, 1-ahead prefetch (stage(t+1) issued before
// compute(t), one barrier/K-tile) + setprio around MFMA clusters.
// ---------------------------------------------------------------------------

typedef unsigned int u32;
typedef unsigned short u16;
typedef __attribute__((ext_vector_type(8))) short short8;   // 8 x bf16 raw
typedef __attribute__((ext_vector_type(4))) float f32x4;

#define GLOBAL_AS __attribute__((address_space(1)))
#define LDS_AS    __attribute__((address_space(3)))

constexpr int D = 1024;
constexpr float EXPM_SCALE = 1.0f / 8.0f;   // s = 3 squarings

__device__ __forceinline__ u16 f2bf(float f) {
  union { float f; u32 u; } v; v.f = f;
  u32 r = (v.u + 0x7FFFu + ((v.u >> 16) & 1u)) >> 16;
  return (u16)r;
}
__device__ __forceinline__ float bf2f(u16 u) {
  union { u32 u; float f; } v; v.u = ((u32)u) << 16;
  return v.f;
}

// async global->LDS, 16B per lane; lds base must be wave-uniform.
__device__ __forceinline__ void g2l16(const void* g, void* l) {
  __builtin_amdgcn_global_load_lds((const GLOBAL_AS u32*)g, (LDS_AS u32*)l,
                                   16, 0, 0);
}

// ---------------------------------------------------------------------------
// normalize rows of x -> bf16
__global__ __launch_bounds__(256) void normalize_kernel(
    const float* __restrict__ x, u16* __restrict__ Xn) {
  const int r = blockIdx.x;
  const int t = threadIdx.x;
  const float4 v = ((const float4*)(x + (size_t)r * D))[t];
  float ss = v.x * v.x + v.y * v.y + v.z * v.z + v.w * v.w;
  for (int o = 32; o; o >>= 1) ss += __shfl_down(ss, o);
  __shared__ float s4[4];
  if ((t & 63) == 0) s4[t >> 6] = ss;
  __syncthreads();
  const float tot = s4[0] + s4[1] + s4[2] + s4[3];
  const float inv = rsqrtf(fmaxf(tot, 1e-12f));
  ushort4 o4;
  o4.x = f2bf(v.x * inv); o4.y = f2bf(v.y * inv);
  o4.z = f2bf(v.z * inv); o4.w = f2bf(v.w * inv);
  ((ushort4*)(Xn + (size_t)r * D))[t] = o4;
}

// ---------------------------------------------------------------------------
// softmax over D=1024 values, one block of 1024 threads
__global__ __launch_bounds__(1024) void gate_kernel(
    const float* __restrict__ g, float* __restrict__ pout) {
  __shared__ float red[16];
  const int t = threadIdx.x;
  const float v = g[t];
  float m = v;
  for (int o = 32; o; o >>= 1) m = fmaxf(m, __shfl_xor(m, o));
  if ((t & 63) == 0) red[t >> 6] = m;
  __syncthreads();
  float M = red[0];
  for (int i = 1; i < 16; ++i) M = fmaxf(M, red[i]);
  const float e = __expf(v - M);
  float s = e;
  for (int o = 32; o; o >>= 1) s += __shfl_xor(s, o);
  __syncthreads();
  if ((t & 63) == 0) red[t >> 6] = s;
  __syncthreads();
  float S = 0.f;
  for (int i = 0; i < 16; ++i) S += red[i];
  pout[t] = e / S;
}

// ---------------------------------------------------------------------------
// X = (M - M^T) * EXPM_SCALE -> bf16.  z: 0 -> Mr, 1 -> Mi
__global__ __launch_bounds__(256) void skew_kernel(
    const float* __restrict__ Mr, const float* __restrict__ Mi,
    u16* X0, u16* X1) {
  const float* M = (blockIdx.z == 0) ? Mr : Mi;
  u16* X = (blockIdx.z == 0) ? X0 : X1;
  __shared__ float t2[64][67];
  const int t = threadIdx.x, bi = blockIdx.x, bj = blockIdx.y;
  const int r0 = t >> 4, c0 = (t & 15) * 4;
  float4 own[4];
#pragma unroll
  for (int i = 0; i < 4; ++i) {
    const int r = i * 16 + r0;
    own[i] = *(const float4*)(M + (size_t)(bi * 64 + r) * D + bj * 64 + c0);
    const float4 tr =
        *(const float4*)(M + (size_t)(bj * 64 + r) * D + bi * 64 + c0);
    t2[r][c0 + 0] = tr.x; t2[r][c0 + 1] = tr.y;
    t2[r][c0 + 2] = tr.z; t2[r][c0 + 3] = tr.w;
  }
  __syncthreads();
#pragma unroll
  for (int i = 0; i < 4; ++i) {
    const int r = i * 16 + r0;
    const float o[4] = {own[i].x, own[i].y, own[i].z, own[i].w};
    ushort4 hv;
    u16* hp = (u16*)&hv;
#pragma unroll
    for (int j = 0; j < 4; ++j)
      hp[j] = f2bf((o[j] - t2[c0 + j][r]) * EXPM_SCALE);
    *(ushort4*)(X + (size_t)(bi * 64 + r) * D + bj * 64 + c0) = hv;
  }
}

// ---------------------------------------------------------------------------
// build q0, q1 (f32) and P1 (bf16) from X..X4 elementwise.
struct QJob {
  const u16 *X, *X2, *X3, *X4;
  float *q0, *q1;
  u16 *P1;
};
struct QJobs { QJob j[2]; };
__global__ __launch_bounds__(256) void build_q_kernel(QJobs jobs) {
  const QJob jb = jobs.j[blockIdx.y];
  const size_t idx0 = ((size_t)blockIdx.x * 256 + threadIdx.x) * 4;
  const int i = (int)(idx0 >> 10);
  const int j0 = (int)(idx0 & 1023);
  const ushort4 xv = *(const ushort4*)(jb.X + idx0);
  const ushort4 x2v = *(const ushort4*)(jb.X2 + idx0);
  const ushort4 x3v = *(const ushort4*)(jb.X3 + idx0);
  const ushort4 x4v = *(const ushort4*)(jb.X4 + idx0);
  float4 q0v, q1v;
  ushort4 p1v;
  u16* p1p = (u16*)&p1v;
  constexpr float c8 = 1.f / 40320.f, c9 = 1.f / 362880.f,
                  c10 = 1.f / 3628800.f, c11 = 1.f / 39916800.f,
                  c12 = 1.f / 479001600.f;
#pragma unroll
  for (int k = 0; k < 4; ++k) {
    const float d = (i == (j0 + k)) ? 1.f : 0.f;
    const float x = bf2f(((const u16*)&xv)[k]);
    const float x2 = bf2f(((const u16*)&x2v)[k]);
    const float x3 = bf2f(((const u16*)&x3v)[k]);
    const float x4 = bf2f(((const u16*)&x4v)[k]);
    ((float*)&q0v)[k] = d + x + x2 * 0.5f + x3 * (1.f / 6.f);
    ((float*)&q1v)[k] = d * (1.f / 24.f) + x * (1.f / 120.f) +
                        x2 * (1.f / 720.f) + x3 * (1.f / 5040.f);
    p1p[k] = f2bf(d * c8 + x * c9 + x2 * c10 + x3 * c11 + x4 * c12);
  }
  *(float4*)(jb.q0 + idx0) = q0v;
  *(float4*)(jb.q1 + idx0) = q1v;
  *(ushort4*)(jb.P1 + idx0) = p1v;
}

// ---------------------------------------------------------------------------
// chain GEMM (r3 version, known-good): Dst = alpha*(A*B^T) [+ C], optional
// dual transposed write DT. 64x64 tile, BK=64, 4 waves (2x2, 32x32 each),
// dbuf 1-ahead prefetch.
struct CJob {
  const u16 *A, *B;
  const float* C;
  u16 *Dst, *DT;
  float alpha;
};
struct CJobs { CJob j[4]; };
__global__ __launch_bounds__(256) void gemm_chain_kernel(CJobs jobs) {
  const CJob jb = jobs.j[blockIdx.z];
  const int tid = threadIdx.x;
  const int w = tid >> 6, lane = tid & 63;
  const int wr = w >> 1, wc = w & 1;
  __shared__ u16 ldsA[2][64 * 64], ldsB[2][64 * 64];
  f32x4 acc[2][2];
#pragma unroll
  for (int m = 0; m < 2; ++m)
#pragma unroll
    for (int n = 0; n < 2; ++n) acc[m][n] = f32x4{0.f, 0.f, 0.f, 0.f};

  const int bi = blockIdx.x, bj = blockIdx.y;  // 16 x 16 tiles
  const int r_l = lane >> 3, c_l = lane & 7;

  auto stage = [&](int buf, int kt) {
    const int k0 = kt * 64;
#pragma unroll
    for (int p = 0; p < 2; ++p) {
      const int row = p * 32 + w * 8 + r_l;
      const int chunk = c_l ^ (row & 7);  // inverse swizzle on global source
      g2l16(jb.A + (size_t)(bi * 64 + row) * D + k0 + chunk * 8,
            (u16*)((char*)&ldsA[buf][0] + p * 4096 + w * 1024));
      g2l16(jb.B + (size_t)(bj * 64 + row) * D + k0 + chunk * 8,
            (u16*)((char*)&ldsB[buf][0] + p * 4096 + w * 1024));
    }
  };

  stage(0, 0);
  __syncthreads();
  int buf = 0;
  for (int kt = 0; kt < 16; ++kt) {
    if (kt < 15) stage(buf ^ 1, kt + 1);  // prefetch flies under MFMAs
#pragma unroll
    for (int h = 0; h < 2; ++h) {
      const int kk = h * 32 + (lane >> 4) * 8;
      short8 a[2], b[2];
#pragma unroll
      for (int m = 0; m < 2; ++m) {
        const int row = wr * 32 + m * 16 + (lane & 15);
        const int off = row * 128 + ((kk * 2) ^ ((row & 7) << 4));
        a[m] = *(const short8*)((const char*)&ldsA[buf][0] + off);
      }
#pragma unroll
      for (int n = 0; n < 2; ++n) {
        const int row = wc * 32 + n * 16 + (lane & 15);
        const int off = row * 128 + ((kk * 2) ^ ((row & 7) << 4));
        b[n] = *(const short8*)((const char*)&ldsB[buf][0] + off);
      }
#pragma unroll
      for (int m = 0; m < 2; ++m)
#pragma unroll
        for (int n = 0; n < 2; ++n)
          acc[m][n] = __builtin_amdgcn_mfma_f32_16x16x32_bf16(
              a[m], b[n], acc[m][n], 0, 0, 0);
    }
    __syncthreads();
    buf ^= 1;
  }
  const int or0 = bi * 64 + wr * 32, oc0 = bj * 64 + wc * 32;
#pragma unroll
  for (int m = 0; m < 2; ++m)
#pragma unroll
    for (int n = 0; n < 2; ++n) {
      const int row0 = or0 + m * 16 + (lane >> 4) * 4;
      const int col = oc0 + n * 16 + (lane & 15);
      ushort4 dv;
      u16* dp = (u16*)&dv;
#pragma unroll
      for (int r = 0; r < 4; ++r) {
        float v = acc[m][n][r] * jb.alpha;
        if (jb.C) v += jb.C[(size_t)(row0 + r) * D + col];
        dp[r] = f2bf(v);
        jb.Dst[(size_t)(row0 + r) * D + col] = dp[r];
      }
      if (jb.DT)  // transposed tile: DT[col][row0..row0+3], one 8B store
        *(ushort4*)(jb.DT + (size_t)col * D + row0) = dv;
    }
}

// ---------------------------------------------------------------------------
// main GEMM: out[r][c] = (sum_k Xn[r][k]*W[c][k] + bias[c])^2 * gate[c]
// 256x256 tile, BK=64, 512 threads = 8 waves (2x4; each wave 128x64 out).
// 128 KiB double-buffered LDS, 1-ahead prefetch, setprio on MFMA clusters.
__global__ __launch_bounds__(512, 1) void main_gemm_kernel(
    const u16* __restrict__ Xn, const u16* __restrict__ Wm,
    const float* __restrict__ bias, const float* __restrict__ gate,
    float* __restrict__ out) {
  const int tid = threadIdx.x;
  const int wid = tid >> 6, lane = tid & 63;
  const int wr = wid >> 2, wc = wid & 3;   // 2 x 4 waves
  __shared__ u16 ldsA[2][256 * 64];        // 32 KB per buf
  __shared__ u16 ldsB[2][256 * 64];        // 32 KB per buf
  f32x4 acc[8][4];
#pragma unroll
  for (int m = 0; m < 8; ++m)
#pragma unroll
    for (int n = 0; n < 4; ++n) acc[m][n] = f32x4{0.f, 0.f, 0.f, 0.f};

  const int bi = blockIdx.x, bj = blockIdx.y;   // 128 x 4
  const int r8 = tid >> 3;     // 0..63
  const int c_l = tid & 7;

  auto stage = [&](int buf, int kt) {
    const int k0 = kt * 64;
#pragma unroll
    for (int p = 0; p < 4; ++p) {
      const int row = p * 64 + r8;               // 0..255
      const int chunk = c_l ^ (row & 7);         // inverse swizzle on source
      g2l16(Xn + (size_t)(bi * 256 + row) * D + k0 + chunk * 8,
            (u16*)((char*)&ldsA[buf][0] + p * 8192 + wid * 1024));
      g2l16(Wm + (size_t)(bj * 256 + row) * D + k0 + chunk * 8,
            (u16*)((char*)&ldsB[buf][0] + p * 8192 + wid * 1024));
    }
  };

  stage(0, 0);
  __syncthreads();
  int buf = 0;
  for (int kt = 0; kt < 16; ++kt) {
    if (kt < 15) stage(buf ^ 1, kt + 1);  // 8 loads fly under 64 MFMAs
#pragma unroll
    for (int ks = 0; ks < 2; ++ks) {
      const int kk = ks * 32 + (lane >> 4) * 8;
      short8 a[8], b[4];
#pragma unroll
      for (int m = 0; m < 8; ++m) {
        const int row = wr * 128 + m * 16 + (lane & 15);
        const int off = row * 128 + ((kk * 2) ^ ((row & 7) << 4));
        a[m] = *(const short8*)((const char*)&ldsA[buf][0] + off);
      }
#pragma unroll
      for (int n = 0; n < 4; ++n) {
        const int row = wc * 64 + n * 16 + (lane & 15);
        const int off = row * 128 + ((kk * 2) ^ ((row & 7) << 4));
        b[n] = *(const short8*)((const char*)&ldsB[buf][0] + off);
      }
      __builtin_amdgcn_s_setprio(1);
#pragma unroll
      for (int m = 0; m < 8; ++m)
#pragma unroll
        for (int n = 0; n < 4; ++n)
          acc[m][n] = __builtin_amdgcn_mfma_f32_16x16x32_bf16(
              a[m], b[n], acc[m][n], 0, 0, 0);
      __builtin_amdgcn_s_setprio(0);
    }
    __syncthreads();   // drains vmcnt: next-tile stage landed; buf reusable
    buf ^= 1;
  }
  const int or0 = bi * 256 + wr * 128, oc0 = bj * 256 + wc * 64;
#pragma unroll
  for (int m = 0; m < 8; ++m)
#pragma unroll
    for (int n = 0; n < 4; ++n) {
      const int col = oc0 + n * 16 + (lane & 15);
      const float bc = bias[col], gc = gate[col];
#pragma unroll
      for (int r = 0; r < 4; ++r) {
        const int row = or0 + m * 16 + (lane >> 4) * 4 + r;
        const float t = acc[m][n][r] + bc;
        out[(size_t)row * D + col] = t * t * gc;
      }
    }
}

// ---------------------------------------------------------------------------
extern "C" void kernel_launch(void* const* d_in, const int* in_sizes, int n_in,
                              void* d_out, int out_size, void* d_ws,
                              size_t ws_size, hipStream_t stream) {
  (void)in_sizes; (void)n_in; (void)out_size; (void)ws_size;
  const float* inp = (const float*)d_in[0];
  const float* Mr = (const float*)d_in[1];
  const float* Mi = (const float*)d_in[2];
  const float* bias = (const float*)d_in[3];
  const float* qg = (const float*)d_in[4];
  float* out = (float*)d_out;
  float* gate_out = out + (size_t)32768 * 1024;

  char* ws = (char*)d_ws;
  u16* Xn = (u16*)ws;  // 64 MB
  // per-matrix region (20 MB): 6 bf16 slots (2 MB) + q0,q1 (4 MB f32).
  // slot lifetimes: s0 X->E3, s1 X2->E3t, s2 X3->E1, s3 X4->E2,
  //                 s4 P1->E1t, s5 P2->E2t
  auto slot = [&](int m, int s) -> u16* {
    return (u16*)(ws + 67108864 + (size_t)m * 20971520 + (size_t)s * 2097152);
  };
  auto q0p = [&](int m) -> float* {
    return (float*)(ws + 67108864 + (size_t)m * 20971520 + 12582912);
  };
  auto q1p = [&](int m) -> float* {
    return (float*)(ws + 67108864 + (size_t)m * 20971520 + 16777216);
  };
  u16* W = (u16*)(ws + 67108864 + 2 * 20971520);  // 2 MB; total ~108 MB

  normalize_kernel<<<32768, 256, 0, stream>>>(inp, Xn);
  gate_kernel<<<1, 1024, 0, stream>>>(qg, gate_out);
  skew_kernel<<<dim3(16, 16, 2), 256, 0, stream>>>(Mr, Mi, slot(0, 0),
                                                   slot(1, 0));

  CJobs cj{};
  // C1: X2 = -f(X,X) -> s1
  for (int m = 0; m < 2; ++m)
    cj.j[m] = CJob{slot(m, 0), slot(m, 0), nullptr, slot(m, 1), nullptr, -1.f};
  gemm_chain_kernel<<<dim3(16, 16, 2), 256, 0, stream>>>(cj);
  // C2: X3 = -f(X2,X) -> s2 ; X4 = f(X2,X2) -> s3
  for (int m = 0; m < 2; ++m) {
    cj.j[m * 2 + 0] =
        CJob{slot(m, 1), slot(m, 0), nullptr, slot(m, 2), nullptr, -1.f};
    cj.j[m * 2 + 1] =
        CJob{slot(m, 1), slot(m, 1), nullptr, slot(m, 3), nullptr, 1.f};
  }
  gemm_chain_kernel<<<dim3(16, 16, 4), 256, 0, stream>>>(cj);
  // buildq: q0, q1, P1 -> s4
  QJobs qj{};
  for (int m = 0; m < 2; ++m)
    qj.j[m] = QJob{slot(m, 0), slot(m, 1), slot(m, 2), slot(m, 3),
                   q0p(m),     q1p(m),     slot(m, 4)};
  build_q_kernel<<<dim3(1024, 2), 256, 0, stream>>>(qj);
  // C3: P2 = f(P1,X4)+q1 -> s5
  for (int m = 0; m < 2; ++m)
    cj.j[m] = CJob{slot(m, 4), slot(m, 3), q1p(m), slot(m, 5), nullptr, 1.f};
  gemm_chain_kernel<<<dim3(16, 16, 2), 256, 0, stream>>>(cj);
  // C4: E = f(P2,X4)+q0 -> s0, dual Et -> s1   (X, X2 dead)
  for (int m = 0; m < 2; ++m)
    cj.j[m] = CJob{slot(m, 5), slot(m, 3), q0p(m), slot(m, 0), slot(m, 1), 1.f};
  gemm_chain_kernel<<<dim3(16, 16, 2), 256, 0, stream>>>(cj);
  // sq1: E1 = f(E,Et) -> s2, dual E1t -> s4   (X3, P1 dead)
  for (int m = 0; m < 2; ++m)
    cj.j[m] = CJob{slot(m, 0), slot(m, 1), nullptr, slot(m, 2), slot(m, 4), 1.f};
  gemm_chain_kernel<<<dim3(16, 16, 2), 256, 0, stream>>>(cj);
  // sq2: E2 = f(E1,E1t) -> s3, dual E2t -> s5   (X4, P2 dead)
  for (int m = 0; m < 2; ++m)
    cj.j[m] = CJob{slot(m, 2), slot(m, 4), nullptr, slot(m, 3), slot(m, 5), 1.f};
  gemm_chain_kernel<<<dim3(16, 16, 2), 256, 0, stream>>>(cj);
  // sq3: E3 = f(E2,E2t) -> s0, dual E3t -> s1   (E, Et dead)
  for (int m = 0; m < 2; ++m)
    cj.j[m] = CJob{slot(m, 3), slot(m, 5), nullptr, slot(m, 0), slot(m, 1), 1.f};
  gemm_chain_kernel<<<dim3(16, 16, 2), 256, 0, stream>>>(cj);
  // W = U^T = f(E3t_B, E3_A)
  cj.j[0] = CJob{slot(1, 1), slot(0, 0), nullptr, W, nullptr, 1.f};
  gemm_chain_kernel<<<dim3(16, 16, 1), 256, 0, stream>>>(cj);

  main_gemm_kernel<<<dim3(128, 4), 512, 0, stream>>>(Xn, W, bias, gate_out,
                                                     out);
}